// Round 5
// baseline (143.666 us; speedup 1.0000x reference)
//
#include <hip/hip_runtime.h>
#include <math.h>

// B=16384 rows, C=1000 cols, fp32 -> 16384 fp32. Inputs 131 MB, mostly
// L3-resident (FETCH_SIZE ~64-83 MB/dispatch after harness re-poison).
//
// R8: take load issue away from the register allocator. R1-R7 (seven
// kernels, three structures) all landed at 42-51 us with VGPR_Count 20-32:
// the LLVM scheduler minimizes pressure and remats __restrict__ const
// loads, so only ~2 loads/wave are ever in flight and every row pays
// 8-16 serialized memory round trips (Little's law -> 1.6-1.9 TB/s).
// Fix: inline-asm load batches with explicit "=&v" float4 outputs and
// counted s_waitcnt vmcnt(8) (AITER/HK pattern). The compiler cannot
// split/shrink/remat an asm block: 8 global_load_dwordx4 issue
// back-to-back per row; a 1-deep software pipeline (issue row k+1 ->
// vmcnt(8) -> consume row k FROM REGISTERS) keeps 16 KB/wave in flight,
// single pass over the data, zero LDS, zero barriers.
//
// Chunk layout: one base address per input per row; chunks at byte
// offsets 0/1024/2048/2976 (chunk 3 covers float4 186..249; lanes 0-5
// duplicate float4 186..191 and are masked to -inf, neutral everywhere).

typedef float f32x4 __attribute__((ext_vector_type(4)));

constexpr int kRowBytes    = 4000;   // 1000 fp32
constexpr int kRowsPerWave = 4;

__device__ __forceinline__ void issue8(
    const float* __restrict__ y1, const float* __restrict__ y2,
    int row, int lane,
    f32x4& a0, f32x4& a1, f32x4& a2, f32x4& a3,
    f32x4& b0, f32x4& b1, f32x4& b2, f32x4& b3)
{
    const char* p1 = reinterpret_cast<const char*>(y1)
                     + (size_t)row * kRowBytes + (size_t)lane * 16;
    const char* p2 = reinterpret_cast<const char*>(y2)
                     + (size_t)row * kRowBytes + (size_t)lane * 16;
    asm volatile(
        "global_load_dwordx4 %0, %8, off\n\t"
        "global_load_dwordx4 %1, %8, off offset:1024\n\t"
        "global_load_dwordx4 %2, %8, off offset:2048\n\t"
        "global_load_dwordx4 %3, %8, off offset:2976\n\t"
        "global_load_dwordx4 %4, %9, off\n\t"
        "global_load_dwordx4 %5, %9, off offset:1024\n\t"
        "global_load_dwordx4 %6, %9, off offset:2048\n\t"
        "global_load_dwordx4 %7, %9, off offset:2976\n\t"
        : "=&v"(a0), "=&v"(a1), "=&v"(a2), "=&v"(a3),
          "=&v"(b0), "=&v"(b1), "=&v"(b2), "=&v"(b3)
        : "v"(p1), "v"(p2));
}

// Counted waits: compiler knows nothing about the asm loads, so WE own the
// waitcnt; sched_barrier(0) stops hipcc hoisting consumers past it (rule:
// "memory" clobber does not order register-only VALU).
__device__ __forceinline__ void wait_vmcnt8() {
    asm volatile("s_waitcnt vmcnt(8)" ::: "memory");
    __builtin_amdgcn_sched_barrier(0);
}
__device__ __forceinline__ void wait_vmcnt0() {
    asm volatile("s_waitcnt vmcnt(0)" ::: "memory");
    __builtin_amdgcn_sched_barrier(0);
}

__device__ __forceinline__ float consume_row(
    f32x4 a0, f32x4 a1, f32x4 a2, f32x4 a3,
    f32x4 b0, f32x4 b1, f32x4 b2, f32x4 b3, int lane)
{
    const float NEG = -INFINITY;
    // Lanes 0-5 of chunk 3 duplicate float4 186..191 (already in chunk 2):
    // mask to -inf. Neutral in top-2 and in pass 2 (-inf - finite = -inf).
    if (lane < 6) {
        a3[0]=NEG; a3[1]=NEG; a3[2]=NEG; a3[3]=NEG;
        b3[0]=NEG; b3[1]=NEG; b3[2]=NEG; b3[3]=NEG;
    }
    f32x4 A[4] = {a0, a1, a2, a3};
    f32x4 B[4] = {b0, b1, b2, b3};

    // pass 1: per-lane top-2, both inputs
    float m1=NEG, m2=NEG, n1=NEG, n2=NEG;
#pragma unroll
    for (int c = 0; c < 4; ++c)
#pragma unroll
        for (int e = 0; e < 4; ++e) {
            const float v = A[c][e];
            m2 = fmaxf(m2, fminf(m1, v)); m1 = fmaxf(m1, v);
            const float w = B[c][e];
            n2 = fmaxf(n2, fminf(n1, w)); n1 = fmaxf(n1, w);
        }

    // wave butterfly merge of (top1, top2); m/n chains interleave (ILP)
#pragma unroll
    for (int off = 32; off > 0; off >>= 1) {
        const float o1 = __shfl_xor(m1, off, 64);
        const float o2 = __shfl_xor(m2, off, 64);
        const float p1 = __shfl_xor(n1, off, 64);
        const float p2 = __shfl_xor(n2, off, 64);
        m2 = fmaxf(fminf(m1, o1), fmaxf(m2, o2));
        m1 = fmaxf(m1, o1);
        n2 = fmaxf(fminf(n1, p1), fmaxf(n2, p2));
        n1 = fmaxf(n1, p1);
    }

    // pass 2 over the SAME registers (no re-read).
    // loo(v) = (v==m1) ? m2 : m1 — tie-safe (duplicated max => m2==m1).
    float best = NEG;
#pragma unroll
    for (int c = 0; c < 4; ++c)
#pragma unroll
        for (int e = 0; e < 4; ++e) {
            const float v = A[c][e];
            const float w = B[c][e];
            const float l1 = (v == m1) ? m2 : m1;
            const float l2 = (w == n1) ? n2 : n1;
            best = fmaxf(best, fminf(v - l1, w - l2));
        }
#pragma unroll
    for (int off = 32; off > 0; off >>= 1)
        best = fmaxf(best, __shfl_xor(best, off, 64));
    return best;
}

__global__ __launch_bounds__(256, 4) void netsat_kernel(
    const float* __restrict__ y1, const float* __restrict__ y2,
    float* __restrict__ out, int nrows)
{
    const int lane = threadIdx.x & 63;
    const int wid  = blockIdx.x * 4 + (threadIdx.x >> 6);
    const int r0   = wid * kRowsPerWave;
    if (r0 >= nrows) return;

    const int last = nrows - 1;
    const int r1r = (r0+1 < nrows) ? r0+1 : last;
    const int r2r = (r0+2 < nrows) ? r0+2 : last;
    const int r3r = (r0+3 < nrows) ? r0+3 : last;

    f32x4 xa0,xa1,xa2,xa3, xb0,xb1,xb2,xb3;   // set X (rows 0,2)
    f32x4 ya0,ya1,ya2,ya3, yb0,yb1,yb2,yb3;   // set Y (rows 1,3)

    // software pipeline: issue k+1, wait oldest 8, consume k from registers
    issue8(y1, y2, r0,  lane, xa0,xa1,xa2,xa3, xb0,xb1,xb2,xb3);
    issue8(y1, y2, r1r, lane, ya0,ya1,ya2,ya3, yb0,yb1,yb2,yb3);

    wait_vmcnt8();
    {
        const float best = consume_row(xa0,xa1,xa2,xa3, xb0,xb1,xb2,xb3, lane);
        if (lane == 0) out[r0] = best;
    }
    issue8(y1, y2, r2r, lane, xa0,xa1,xa2,xa3, xb0,xb1,xb2,xb3);

    wait_vmcnt8();
    if (r0+1 < nrows) {
        const float best = consume_row(ya0,ya1,ya2,ya3, yb0,yb1,yb2,yb3, lane);
        if (lane == 0) out[r0+1] = best;
    }
    issue8(y1, y2, r3r, lane, ya0,ya1,ya2,ya3, yb0,yb1,yb2,yb3);

    wait_vmcnt8();
    if (r0+2 < nrows) {
        const float best = consume_row(xa0,xa1,xa2,xa3, xb0,xb1,xb2,xb3, lane);
        if (lane == 0) out[r0+2] = best;
    }

    wait_vmcnt0();
    if (r0+3 < nrows) {
        const float best = consume_row(ya0,ya1,ya2,ya3, yb0,yb1,yb2,yb3, lane);
        if (lane == 0) out[r0+3] = best;
    }
}

extern "C" void kernel_launch(void* const* d_in, const int* in_sizes, int n_in,
                              void* d_out, int out_size, void* d_ws, size_t ws_size,
                              hipStream_t stream) {
    const float* y1 = (const float*)d_in[0];
    const float* y2 = (const float*)d_in[1];
    float* out = (float*)d_out;
    const int nrows = out_size;  // 16384
    // 4 waves/block * 4 rows/wave = 16 rows per block; 1024 blocks for 16384
    // rows = 4 blocks/CU, fully resident in one dispatch.
    const int blocks = (nrows + 16 - 1) / 16;
    netsat_kernel<<<blocks, 256, 0, stream>>>(y1, y2, out, nrows);
}

// Round 6
// 137.518 us; speedup vs baseline: 1.0447x; 1.0447x over previous
//
#include <hip/hip_runtime.h>
#include <math.h>

// B=16384 rows, C=1000 cols, fp32 -> 16384 fp32.
//
// R9 = revert to R5 (best measured: kernel 41.2 us, bench 140.385).
//
// ROOFLINE EVIDENCE accumulated over R1-R8 (eight structures, 42-51 us):
//  * Warm-cache replay dispatches (hbm_bytes 0.13-0.52 MB, i.e. ~zero HBM
//    traffic) still take 41-44 us across THREE grid structures including
//    a persistent dispatch-free one -> the limit is the L3/fabric READ
//    path at ~3.1-3.2 TB/s delivered, not HBM, not latency, not dispatch.
//  * m13 copy = 6.29 TB/s (read+write) -> ~3.15 TB/s per direction;
//    fillBuffer proves write-alone = 6.5 TB/s; reads cap at ~3.15.
//  * R7 exceeded it (5.8 TB/s delivered) only via L1/L2-resident
//    re-reads BELOW the fabric; its fresh stream sat at 2.9 TB/s.
//  * Floor = 131.07 MB / 3.15 TB/s = 41.6 us. This kernel measures
//    41.2-42.6 us = at the floor. Pipelining (R6), asm load batches (R8),
//    register residency (R3/R4), persistence (R7) all failed to move it.
//
// Structure: one block per row, 256 threads, each thread owns ONE float4
// of y1 + ONE of y2 (8 VGPRs payload -> no allocator fight, VGPR=20).
// Cross-wave top-2 merge via 16-float LDS; every thread merges the 4
// wave-results itself (no broadcast barrier needed).

constexpr int kC  = 1000;
constexpr int kNV = kC / 4;        // 250 float4 per row; threads 250..255 pad

__global__ __launch_bounds__(256, 8) void netsat_kernel(
    const float* __restrict__ y1, const float* __restrict__ y2,
    float* __restrict__ out, int nrows)
{
    const int tid  = threadIdx.x;
    const int lane = tid & 63;
    const int wave = tid >> 6;
    const int row  = blockIdx.x;
    if (row >= nrows) return;

    const float4* r1 = reinterpret_cast<const float4*>(y1) + (size_t)row * kNV;
    const float4* r2 = reinterpret_cast<const float4*>(y2) + (size_t)row * kNV;

    // Unconditional clamped loads (branchless), mask pad threads after load.
    const int vi = (tid < kNV) ? tid : (kNV - 1);
    float4 a = r1[vi];
    float4 b = r2[vi];
    if (tid >= kNV) {
        a = make_float4(-INFINITY, -INFINITY, -INFINITY, -INFINITY);
        b = make_float4(-INFINITY, -INFINITY, -INFINITY, -INFINITY);
    }

    // ---- local top-2 over this thread's 4 elements, both inputs ----
    float m1 = -INFINITY, m2 = -INFINITY;   // y1 top-2
    float n1 = -INFINITY, n2 = -INFINITY;   // y2 top-2
    {
        const float* av = reinterpret_cast<const float*>(&a);
        const float* bv = reinterpret_cast<const float*>(&b);
#pragma unroll
        for (int k = 0; k < 4; ++k) {
            const float v = av[k];
            m2 = fmaxf(m2, fminf(m1, v)); m1 = fmaxf(m1, v);
            const float w = bv[k];
            n2 = fmaxf(n2, fminf(n1, w)); n1 = fmaxf(n1, w);
        }
    }

    // ---- wave butterfly merge of (top1, top2); m/n chains interleave ----
#pragma unroll
    for (int off = 32; off > 0; off >>= 1) {
        const float o1 = __shfl_xor(m1, off, 64);
        const float o2 = __shfl_xor(m2, off, 64);
        const float p1 = __shfl_xor(n1, off, 64);
        const float p2 = __shfl_xor(n2, off, 64);
        m2 = fmaxf(fminf(m1, o1), fmaxf(m2, o2));
        m1 = fmaxf(m1, o1);
        n2 = fmaxf(fminf(n1, p1), fmaxf(n2, p2));
        n1 = fmaxf(n1, p1);
    }

    // ---- cross-wave merge via LDS; every thread merges all 4 wave results
    __shared__ float sm[4][4];     // [wave] = {m1, m2, n1, n2}
    __shared__ float sbest[4];
    if (lane == 0) {
        sm[wave][0] = m1; sm[wave][1] = m2;
        sm[wave][2] = n1; sm[wave][3] = n2;
    }
    __syncthreads();

    float M1 = -INFINITY, M2 = -INFINITY, N1 = -INFINITY, N2 = -INFINITY;
#pragma unroll
    for (int w = 0; w < 4; ++w) {
        const float w1 = sm[w][0], w2 = sm[w][1];
        M2 = fmaxf(fminf(M1, w1), fmaxf(M2, w2));
        M1 = fmaxf(M1, w1);
        const float u1 = sm[w][2], u2 = sm[w][3];
        N2 = fmaxf(fminf(N1, u1), fmaxf(N2, u2));
        N1 = fmaxf(N1, u1);
    }

    // ---- pass 2 over REGISTER payload: max_j min(v - loo1, w - loo2) ----
    // loo(v) = (v==M1) ? M2 : M1 — tie-safe (duplicated max => M2==M1).
    float best = -INFINITY;
    {
        const float* av = reinterpret_cast<const float*>(&a);
        const float* bv = reinterpret_cast<const float*>(&b);
#pragma unroll
        for (int k = 0; k < 4; ++k) {
            const float v = av[k];
            const float w = bv[k];
            const float l1 = (v == M1) ? M2 : M1;
            const float l2 = (w == N1) ? N2 : N1;
            best = fmaxf(best, fminf(v - l1, w - l2));
        }
    }
#pragma unroll
    for (int off = 32; off > 0; off >>= 1)
        best = fmaxf(best, __shfl_xor(best, off, 64));

    if (lane == 0) sbest[wave] = best;
    __syncthreads();

    if (tid == 0) {
        float r = fmaxf(fmaxf(sbest[0], sbest[1]), fmaxf(sbest[2], sbest[3]));
        out[row] = r;
    }
}

extern "C" void kernel_launch(void* const* d_in, const int* in_sizes, int n_in,
                              void* d_out, int out_size, void* d_ws, size_t ws_size,
                              hipStream_t stream) {
    const float* y1 = (const float*)d_in[0];
    const float* y2 = (const float*)d_in[1];
    float* out = (float*)d_out;
    const int nrows = out_size;  // 16384
    netsat_kernel<<<nrows, 256, 0, stream>>>(y1, y2, out, nrows);
}